// Round 1
// baseline (165.793 us; speedup 1.0000x reference)
//
#include <hip/hip_runtime.h>
#include <hip/hip_bf16.h>
#include <stdint.h>

#define BATCH 4096
#define KGRP  8
#define BLK   1024
#define TOTAL 8192

#define BM 128
#define BN 128
#define BK 32

typedef __attribute__((ext_vector_type(8))) short short8;
typedef __attribute__((ext_vector_type(4))) float f32x4;

// ---------- helpers ----------

__device__ __forceinline__ unsigned short f2bf(float f) {
    union { float f; uint32_t u; } c; c.f = f;
    uint32_t u = c.u;
    u += 0x7fffu + ((u >> 16) & 1u);   // round-to-nearest-even
    return (unsigned short)(u >> 16);
}

__device__ __forceinline__ float fast_tanh(float x) {
    // tanh(x) = 1 - 2/(exp(2x)+1); exact at +-inf limits, ~1e-6 rel err (<< bf16 rounding)
    float e = __expf(2.0f * x);
    return 1.0f - 2.0f / (e + 1.0f);
}

// XOR swizzle: permute 16B chunks (bits 4-5) by row-pair (bits 7-8).
// Involution; keeps 16B alignment; row (bits>=6) unchanged.
__device__ __forceinline__ uint32_t swz(uint32_t p) {
    return p ^ (((p >> 7) & 3u) << 4);
}

// ---------- pass 1: tanh(v) -> bf16, W -> bf16 ----------

__global__ void k_tanh_cast(const float4* __restrict__ v, ushort4* __restrict__ H) {
    const int n4 = BATCH * TOTAL / 4;            // 8388608
    int i = blockIdx.x * blockDim.x + threadIdx.x;
    const int stride = gridDim.x * blockDim.x;
    for (; i < n4; i += stride) {
        float4 f = v[i];
        ushort4 o;
        o.x = f2bf(fast_tanh(f.x));
        o.y = f2bf(fast_tanh(f.y));
        o.z = f2bf(fast_tanh(f.z));
        o.w = f2bf(fast_tanh(f.w));
        H[i] = o;
    }
}

__global__ void k_wcast(const float4* __restrict__ W, ushort4* __restrict__ Wb) {
    const int n4 = KGRP * BLK * BLK / 4;         // 2097152
    int i = blockIdx.x * blockDim.x + threadIdx.x;
    const int stride = gridDim.x * blockDim.x;
    for (; i < n4; i += stride) {
        float4 f = W[i];
        ushort4 o;
        o.x = f2bf(f.x); o.y = f2bf(f.y); o.z = f2bf(f.z); o.w = f2bf(f.w);
        Wb[i] = o;
    }
}

// ---------- pass 2: grouped GEMM, 128x128 tile, mfma 16x16x32 bf16 ----------
// C[m][n] = sum_k H[m][k] * W[n][k]  (B^T layout), epilogue fuses x + bias.

__global__ __launch_bounds__(256, 2)
void k_gemm(const unsigned short* __restrict__ H, const unsigned short* __restrict__ Wb,
            const float* __restrict__ x, const float* __restrict__ bias,
            float* __restrict__ out) {
    __shared__ __attribute__((aligned(16))) unsigned short As[BM * BK];  // 8 KB
    __shared__ __attribute__((aligned(16))) unsigned short Bs[BN * BK];  // 8 KB

    // XCD swizzle: blockIdx.x % 8 == XCD (assumed round-robin). Each XCD owns one
    // group g entirely -> Wb[g] (2MB bf16) stays L2-resident; ntile fastest so the
    // 8 blocks sharing an A M-panel are consecutive on one XCD.
    const int h = blockIdx.x;                 // 0..2047
    const int flat = (h & 7) * 256 + (h >> 3);
    const int g = flat >> 8;                  // 0..7
    const int mtile = (flat >> 3) & 31;       // 0..31
    const int ntile = flat & 7;               // 0..7

    const int tid = threadIdx.x;
    const int lane = tid & 63;
    const int w = tid >> 6;
    const int wr = w >> 1, wc = w & 1;        // 2x2 waves -> 64x64 output each

    // Staging: issue s in {0,1}; thread t fills physical LDS byte p = s*4096+t*16
    // (global_load_lds writes wave-uniform base + lane*16, linearly).
    // Pre-swizzle the SOURCE so that LDS[p] holds logical element swz(p).
    int rS[2], cS[2];
#pragma unroll
    for (int s = 0; s < 2; ++s) {
        uint32_t p = (uint32_t)(s * 4096 + tid * 16);
        uint32_t q = swz(p);
        rS[s] = (int)(q >> 6);          // tile row 0..127
        cS[s] = (int)((q & 63u) >> 1);  // element col 0..31 (multiple of 8)
    }
    const unsigned short* Abase = H  + (size_t)(mtile * BM) * TOTAL + (size_t)g * BLK;
    const unsigned short* Bbase = Wb + ((size_t)g * BLK + (size_t)ntile * BN) * BLK;
    const uint32_t ldsWaveBase = (uint32_t)(w << 10);   // w*1024 bytes

    // Fragment LDS offsets (physical = swz(logical)), constant across K loop.
    uint32_t aoff[4], boff[4];
#pragma unroll
    for (int m = 0; m < 4; ++m) {
        uint32_t row = (uint32_t)(wr * 64 + m * 16 + (lane & 15));
        aoff[m] = swz(row * 64u + (uint32_t)(lane >> 4) * 16u);
    }
#pragma unroll
    for (int n = 0; n < 4; ++n) {
        uint32_t row = (uint32_t)(wc * 64 + n * 16 + (lane & 15));
        boff[n] = swz(row * 64u + (uint32_t)(lane >> 4) * 16u);
    }

    f32x4 acc[4][4];
#pragma unroll
    for (int m = 0; m < 4; ++m)
#pragma unroll
        for (int n = 0; n < 4; ++n) acc[m][n] = (f32x4){0.f, 0.f, 0.f, 0.f};

    const char* AsB = (const char*)As;
    const char* BsB = (const char*)Bs;

    for (int kt = 0; kt < BLK / BK; ++kt) {
        const unsigned short* Ak = Abase + kt * BK;
        const unsigned short* Bk = Bbase + kt * BK;
#pragma unroll
        for (int s = 0; s < 2; ++s) {
            __builtin_amdgcn_global_load_lds(
                (const __attribute__((address_space(1))) uint32_t*)(Ak + (size_t)rS[s] * TOTAL + cS[s]),
                (__attribute__((address_space(3))) uint32_t*)((char*)As + s * 4096 + ldsWaveBase),
                16, 0, 0);
            __builtin_amdgcn_global_load_lds(
                (const __attribute__((address_space(1))) uint32_t*)(Bk + (size_t)rS[s] * BLK + cS[s]),
                (__attribute__((address_space(3))) uint32_t*)((char*)Bs + s * 4096 + ldsWaveBase),
                16, 0, 0);
        }
        __syncthreads();   // drains vmcnt before LDS reads

        short8 af[4], bf8[4];
#pragma unroll
        for (int m = 0; m < 4; ++m) af[m] = *(const short8*)(AsB + aoff[m]);
#pragma unroll
        for (int n = 0; n < 4; ++n) bf8[n] = *(const short8*)(BsB + boff[n]);
#pragma unroll
        for (int m = 0; m < 4; ++m)
#pragma unroll
            for (int n = 0; n < 4; ++n)
                acc[m][n] = __builtin_amdgcn_mfma_f32_16x16x32_bf16(af[m], bf8[n], acc[m][n], 0, 0, 0);
        __syncthreads();   // protect LDS before next stage
    }

    // Epilogue: out[row][gout*1024+col] = x[...] + bias[g*1024+col] + acc
    // C/D mapping (m89/m91): col = lane&15, row = (lane>>4)*4 + reg
    const int gout = (g + 1) & 7;
    const int row0 = mtile * BM + wr * 64 + ((lane >> 4) << 2);
    const int col0 = ntile * BN + wc * 64 + (lane & 15);
    float bv[4];
#pragma unroll
    for (int n = 0; n < 4; ++n) bv[n] = bias[g * BLK + col0 + n * 16];
#pragma unroll
    for (int m = 0; m < 4; ++m) {
#pragma unroll
        for (int j = 0; j < 4; ++j) {
            const int row = row0 + m * 16 + j;
            const size_t base = (size_t)row * TOTAL + (size_t)gout * BLK;
#pragma unroll
            for (int n = 0; n < 4; ++n) {
                const size_t idx = base + col0 + n * 16;
                out[idx] = x[idx] + bv[n] + acc[m][n][j];
            }
        }
    }
}

// ---------- fallback (ws too small): correct but slow ----------

__global__ void k_naive(const float* __restrict__ x, const float* __restrict__ v,
                        const float* __restrict__ W, const float* __restrict__ b,
                        float* __restrict__ out) {
    __shared__ float hv[BLK];
    const int bid = blockIdx.x;
    const int quarter = bid & 3;
    const int g = (bid >> 2) & 7;
    const int row = bid >> 5;
    for (int i = threadIdx.x; i < BLK; i += 256)
        hv[i] = tanhf(v[(size_t)row * TOTAL + g * BLK + i]);
    __syncthreads();
    const int o = quarter * 256 + threadIdx.x;
    const float* wrow = W + ((size_t)g * BLK + o) * BLK;
    float s = 0.f;
    for (int i = 0; i < BLK; ++i) s += hv[i] * wrow[i];
    const size_t oi = (size_t)row * TOTAL + (size_t)((g + 1) & 7) * BLK + o;
    out[oi] = x[oi] + b[g * BLK + o] + s;
}

// ---------- launch ----------

extern "C" void kernel_launch(void* const* d_in, const int* in_sizes, int n_in,
                              void* d_out, int out_size, void* d_ws, size_t ws_size,
                              hipStream_t stream) {
    const float* x = (const float*)d_in[0];
    const float* v = (const float*)d_in[1];
    const float* W = (const float*)d_in[2];
    const float* b = (const float*)d_in[3];
    float* out = (float*)d_out;

    const size_t needH = (size_t)BATCH * TOTAL * sizeof(unsigned short);      // 64 MB
    const size_t needW = (size_t)KGRP * BLK * BLK * sizeof(unsigned short);   // 16 MB

    if (ws_size >= needH + needW) {
        unsigned short* H  = (unsigned short*)d_ws;
        unsigned short* Wb = (unsigned short*)((char*)d_ws + needH);
        k_tanh_cast<<<2048, 256, 0, stream>>>((const float4*)v, (ushort4*)H);
        k_wcast<<<1024, 256, 0, stream>>>((const float4*)W, (ushort4*)Wb);
        k_gemm<<<2048, 256, 0, stream>>>(H, Wb, x, b, out);
    } else {
        k_naive<<<BATCH * KGRP * 4, 256, 0, stream>>>(x, v, W, b, out);
    }
}

// Round 2
// 161.011 us; speedup vs baseline: 1.0297x; 1.0297x over previous
//
#include <hip/hip_runtime.h>
#include <hip/hip_bf16.h>
#include <stdint.h>

#define BATCH 4096
#define KGRP  8
#define BLK   1024
#define TOTAL 8192

typedef __attribute__((ext_vector_type(8))) short short8;
typedef __attribute__((ext_vector_type(4))) float f32x4;

// ---------- helpers ----------

__device__ __forceinline__ unsigned short f2bf(float f) {
    union { float f; uint32_t u; } c; c.f = f;
    uint32_t u = c.u;
    u += 0x7fffu + ((u >> 16) & 1u);   // round-to-nearest-even
    return (unsigned short)(u >> 16);
}

__device__ __forceinline__ float fast_tanh(float x) {
    float e = __expf(2.0f * x);
    return 1.0f - 2.0f / (e + 1.0f);
}

// ---------- pass 1: tanh(v) -> bf16, W -> bf16 ----------

__global__ void k_tanh_cast(const float4* __restrict__ v, ushort4* __restrict__ H) {
    const int n4 = BATCH * TOTAL / 4;
    int i = blockIdx.x * blockDim.x + threadIdx.x;
    const int stride = gridDim.x * blockDim.x;
    for (; i < n4; i += stride) {
        float4 f = v[i];
        ushort4 o;
        o.x = f2bf(fast_tanh(f.x));
        o.y = f2bf(fast_tanh(f.y));
        o.z = f2bf(fast_tanh(f.z));
        o.w = f2bf(fast_tanh(f.w));
        H[i] = o;
    }
}

__global__ void k_wcast(const float4* __restrict__ W, ushort4* __restrict__ Wb) {
    const int n4 = KGRP * BLK * BLK / 4;
    int i = blockIdx.x * blockDim.x + threadIdx.x;
    const int stride = gridDim.x * blockDim.x;
    for (; i < n4; i += stride) {
        float4 f = W[i];
        ushort4 o;
        o.x = f2bf(f.x); o.y = f2bf(f.y); o.z = f2bf(f.z); o.w = f2bf(f.w);
        Wb[i] = o;
    }
}

// ---------- pass 2: grouped GEMM, 256x256 tile, BK=64, 8 waves, 4-phase/tile ----------
// C[m][n] = sum_k H[m][k] * W[n][k]; epilogue fuses x + bias.
//
// LDS: 2 buffers x (A[256][64] + B[256][64]) bf16 = 128 KiB.
// st_16x32 swizzle: phys_byte = log_byte ^ (((log_byte>>9)&1)<<5), applied on BOTH
// the staging source (pre-swizzled global addr, LDS written linearly by
// global_load_lds) and the ds_read offsets (rule #21).
//
// Schedule per K-tile t (buf = cur; staging tile t+1 -> cur^1):
//   ph0: ds_read all 8 B-frags + A m0,m1; issue A-stage (4 gload_lds);  bar; MFMA(16); bar
//   ph1: ds_read A m2,m3;               issue B-stage (4 gload_lds);    bar; MFMA(16); bar
//   ph2: ds_read A m4,m5;                                               bar; MFMA(16); bar
//   ph3: ds_read A m6,m7;                                               bar; MFMA(16);
//        s_waitcnt vmcnt(0); bar   <- single drain per tile; youngest staged load
//                                      was issued 2 phases earlier (in-flight covered)
// Race-freedom: reads of buf^1 (tile t-1) all complete before the boundary barrier
// that precedes the first stage-issue into buf^1; readers of tile t+1 are gated by
// every wave's own vmcnt(0) + the boundary barrier (vmcnt is per-wave; each wave
// waits for its own DMA shares, barrier publishes all).

__global__ __launch_bounds__(512, 2)
void k_gemm(const unsigned short* __restrict__ H, const unsigned short* __restrict__ Wb,
            const float* __restrict__ x, const float* __restrict__ bias,
            float* __restrict__ out) {
    __shared__ __attribute__((aligned(1024))) char lds[131072];

    // T1: XCD swizzle. bid&7 == XCD (round-robin dispatch); each XCD owns one group
    // -> Wb[g] (2MB) L2-resident; 4 consecutive slots share one A M-panel.
    const int bid   = blockIdx.x;            // 0..511
    const int g     = bid & 7;
    const int slot  = bid >> 3;               // 0..63
    const int mtile = slot >> 2;               // 0..15
    const int ntile = slot & 3;                // 0..3

    const int tid  = threadIdx.x;
    const int lane = tid & 63;
    const int w    = tid >> 6;                 // 0..7
    const int wr   = w >> 2;                   // 0..1  (M)
    const int wc   = w & 3;                    // 0..3  (N)

    // ds_read physical offsets. swizzle flip depends only on (lane>>2)&1 because
    // byte-bit-9 == row-bit-2 == lane-bit-2 for our fragment rows.
    const uint32_t flip  = (uint32_t)(((lane >> 2) & 1) << 5);
    const uint32_t kcol  = ((uint32_t)((lane >> 4) * 16)) ^ flip;
    const uint32_t aBase = (uint32_t)(wr * 128 + (lane & 15)) * 128u + kcol;            // A region @0
    const uint32_t bBase = 32768u + (uint32_t)(wc * 64 + (lane & 15)) * 128u + kcol;    // B region @32K

    // staging: thread tid covers physical LDS bytes chunk*8192 + tid*16; the logical
    // element there is the swizzled offset -> pre-swizzle the global source.
    const int sRow = tid >> 3;                                        // 0..63 (in 64-row chunk)
    const int sCol = ((tid & 7) * 8) ^ (((tid >> 5) & 1) << 4);       // element col 0..63
    const unsigned short* Asrc0 = H  + ((size_t)(mtile * 256) + sRow) * TOTAL + (size_t)g * BLK + sCol;
    const unsigned short* Bsrc0 = Wb + ((size_t)g * BLK * BLK) + ((size_t)(ntile * 256) + sRow) * BLK + sCol;
    const uint32_t ldsStageBase = (uint32_t)(w << 10);   // wave-uniform; HW adds lane*16

    auto stageA = [&](int kt, uint32_t bufb) {
#pragma unroll
        for (int c = 0; c < 4; ++c)
            __builtin_amdgcn_global_load_lds(
                (const __attribute__((address_space(1))) uint32_t*)(Asrc0 + (size_t)(c * 64) * TOTAL + kt * 64),
                (__attribute__((address_space(3))) uint32_t*)(lds + bufb + c * 8192 + ldsStageBase),
                16, 0, 0);
    };
    auto stageB = [&](int kt, uint32_t bufb) {
#pragma unroll
        for (int c = 0; c < 4; ++c)
            __builtin_amdgcn_global_load_lds(
                (const __attribute__((address_space(1))) uint32_t*)(Bsrc0 + (size_t)(c * 64) * BLK + kt * 64),
                (__attribute__((address_space(3))) uint32_t*)(lds + bufb + 32768u + c * 8192 + ldsStageBase),
                16, 0, 0);
    };

    f32x4 acc[8][4];
#pragma unroll
    for (int m = 0; m < 8; ++m)
#pragma unroll
        for (int n = 0; n < 4; ++n) acc[m][n] = (f32x4){0.f, 0.f, 0.f, 0.f};

    // prologue: stage tile 0 into buf0
    stageA(0, 0u);
    stageB(0, 0u);
    asm volatile("s_waitcnt vmcnt(0)" ::: "memory");
    __builtin_amdgcn_s_barrier();
    __builtin_amdgcn_sched_barrier(0);

    uint32_t cur = 0;
    for (int kt = 0; kt < 16; ++kt) {
        const uint32_t bufb = cur << 16;
        const uint32_t nbuf = bufb ^ 65536u;
        const char* Lb = lds + bufb;
        const bool st = (kt < 15);

        short8 bfr[4][2];
        short8 am[2][2];

        // ---------------- phase 0 ----------------
#pragma unroll
        for (int n = 0; n < 4; ++n)
#pragma unroll
            for (int ks = 0; ks < 2; ++ks)
                bfr[n][ks] = *(const short8*)(Lb + bBase + n * 2048 + ks * 64);
#pragma unroll
        for (int i = 0; i < 2; ++i)
#pragma unroll
            for (int ks = 0; ks < 2; ++ks)
                am[i][ks] = *(const short8*)(Lb + aBase + (0 + i) * 2048 + ks * 64);
        if (st) stageA(kt + 1, nbuf);
        __builtin_amdgcn_s_barrier();
        __builtin_amdgcn_s_setprio(1);
#pragma unroll
        for (int i = 0; i < 2; ++i)
#pragma unroll
            for (int n = 0; n < 4; ++n)
#pragma unroll
                for (int ks = 0; ks < 2; ++ks)
                    acc[0 + i][n] = __builtin_amdgcn_mfma_f32_16x16x32_bf16(am[i][ks], bfr[n][ks], acc[0 + i][n], 0, 0, 0);
        __builtin_amdgcn_s_setprio(0);
        __builtin_amdgcn_s_barrier();

        // ---------------- phase 1 ----------------
#pragma unroll
        for (int i = 0; i < 2; ++i)
#pragma unroll
            for (int ks = 0; ks < 2; ++ks)
                am[i][ks] = *(const short8*)(Lb + aBase + (2 + i) * 2048 + ks * 64);
        if (st) stageB(kt + 1, nbuf);
        __builtin_amdgcn_s_barrier();
        __builtin_amdgcn_s_setprio(1);
#pragma unroll
        for (int i = 0; i < 2; ++i)
#pragma unroll
            for (int n = 0; n < 4; ++n)
#pragma unroll
                for (int ks = 0; ks < 2; ++ks)
                    acc[2 + i][n] = __builtin_amdgcn_mfma_f32_16x16x32_bf16(am[i][ks], bfr[n][ks], acc[2 + i][n], 0, 0, 0);
        __builtin_amdgcn_s_setprio(0);
        __builtin_amdgcn_s_barrier();

        // ---------------- phase 2 ----------------
#pragma unroll
        for (int i = 0; i < 2; ++i)
#pragma unroll
            for (int ks = 0; ks < 2; ++ks)
                am[i][ks] = *(const short8*)(Lb + aBase + (4 + i) * 2048 + ks * 64);
        __builtin_amdgcn_s_barrier();
        __builtin_amdgcn_s_setprio(1);
#pragma unroll
        for (int i = 0; i < 2; ++i)
#pragma unroll
            for (int n = 0; n < 4; ++n)
#pragma unroll
                for (int ks = 0; ks < 2; ++ks)
                    acc[4 + i][n] = __builtin_amdgcn_mfma_f32_16x16x32_bf16(am[i][ks], bfr[n][ks], acc[4 + i][n], 0, 0, 0);
        __builtin_amdgcn_s_setprio(0);
        __builtin_amdgcn_s_barrier();

        // ---------------- phase 3 ----------------
#pragma unroll
        for (int i = 0; i < 2; ++i)
#pragma unroll
            for (int ks = 0; ks < 2; ++ks)
                am[i][ks] = *(const short8*)(Lb + aBase + (6 + i) * 2048 + ks * 64);
        __builtin_amdgcn_s_barrier();
        __builtin_amdgcn_s_setprio(1);
#pragma unroll
        for (int i = 0; i < 2; ++i)
#pragma unroll
            for (int n = 0; n < 4; ++n)
#pragma unroll
                for (int ks = 0; ks < 2; ++ks)
                    acc[6 + i][n] = __builtin_amdgcn_mfma_f32_16x16x32_bf16(am[i][ks], bfr[n][ks], acc[6 + i][n], 0, 0, 0);
        __builtin_amdgcn_s_setprio(0);

        // tile boundary: publish buf^1 (single per-tile drain; loads are >=2 phases old)
        asm volatile("s_waitcnt vmcnt(0)" ::: "memory");
        __builtin_amdgcn_s_barrier();
        __builtin_amdgcn_sched_barrier(0);
        cur ^= 1u;
    }

    // ---------------- epilogue: out = x + bias + acc ----------------
    // C/D mapping (m89/m91): col = lane&15, row = (lane>>4)*4 + reg
    const int gout = (g + 1) & 7;
    const int row0 = mtile * 256 + wr * 128 + ((lane >> 4) << 2);
    const int colL = ntile * 256 + wc * 64 + (lane & 15);   // 0..1023 within group
    float bv[4];
#pragma unroll
    for (int n = 0; n < 4; ++n) bv[n] = bias[g * BLK + colL + n * 16];
#pragma unroll
    for (int m = 0; m < 8; ++m) {
#pragma unroll
        for (int j = 0; j < 4; ++j) {
            const int row = row0 + m * 16 + j;
            const size_t base = (size_t)row * TOTAL + (size_t)gout * BLK;
#pragma unroll
            for (int n = 0; n < 4; ++n) {
                const size_t idx = base + colL + n * 16;
                out[idx] = x[idx] + bv[n] + acc[m][n][j];
            }
        }
    }
}

// ---------- fallback (ws too small): correct but slow ----------

__global__ void k_naive(const float* __restrict__ x, const float* __restrict__ v,
                        const float* __restrict__ W, const float* __restrict__ b,
                        float* __restrict__ out) {
    __shared__ float hv[BLK];
    const int bid = blockIdx.x;
    const int quarter = bid & 3;
    const int g = (bid >> 2) & 7;
    const int row = bid >> 5;
    for (int i = threadIdx.x; i < BLK; i += 256)
        hv[i] = tanhf(v[(size_t)row * TOTAL + g * BLK + i]);
    __syncthreads();
    const int o = quarter * 256 + threadIdx.x;
    const float* wrow = W + ((size_t)g * BLK + o) * BLK;
    float s = 0.f;
    for (int i = 0; i < BLK; ++i) s += hv[i] * wrow[i];
    const size_t oi = (size_t)row * TOTAL + (size_t)((g + 1) & 7) * BLK + o;
    out[oi] = x[oi] + b[g * BLK + o] + s;
}

// ---------- launch ----------

extern "C" void kernel_launch(void* const* d_in, const int* in_sizes, int n_in,
                              void* d_out, int out_size, void* d_ws, size_t ws_size,
                              hipStream_t stream) {
    const float* x = (const float*)d_in[0];
    const float* v = (const float*)d_in[1];
    const float* W = (const float*)d_in[2];
    const float* b = (const float*)d_in[3];
    float* out = (float*)d_out;

    const size_t needH = (size_t)BATCH * TOTAL * sizeof(unsigned short);      // 64 MB
    const size_t needW = (size_t)KGRP * BLK * BLK * sizeof(unsigned short);   // 16 MB

    if (ws_size >= needH + needW) {
        unsigned short* H  = (unsigned short*)d_ws;
        unsigned short* Wb = (unsigned short*)((char*)d_ws + needH);
        k_tanh_cast<<<2048, 256, 0, stream>>>((const float4*)v, (ushort4*)H);
        k_wcast<<<1024, 256, 0, stream>>>((const float4*)W, (ushort4*)Wb);
        k_gemm<<<512, 512, 0, stream>>>(H, Wb, x, b, out);
    } else {
        k_naive<<<BATCH * KGRP * 4, 256, 0, stream>>>(x, v, W, b, out);
    }
}

// Round 4
// 155.529 us; speedup vs baseline: 1.0660x; 1.0352x over previous
//
#include <hip/hip_runtime.h>
#include <hip/hip_bf16.h>
#include <stdint.h>

#define BATCH 4096
#define KGRP  8
#define BLK   1024
#define TOTAL 8192

typedef __attribute__((ext_vector_type(8))) short short8;
typedef __attribute__((ext_vector_type(4))) float f32x4;

#define AS1 __attribute__((address_space(1)))
#define AS3 __attribute__((address_space(3)))

// ---------- helpers ----------

__device__ __forceinline__ unsigned short f2bf(float f) {
    union { float f; uint32_t u; } c; c.f = f;
    uint32_t u = c.u;
    u += 0x7fffu + ((u >> 16) & 1u);   // round-to-nearest-even
    return (unsigned short)(u >> 16);
}

__device__ __forceinline__ float fast_tanh(float x) {
    float e = __expf(2.0f * x);
    return 1.0f - 2.0f / (e + 1.0f);
}

// ---------- pass 1: tanh(v) -> bf16, W -> bf16 (both at HBM BW floor) ----------

__global__ void k_tanh_cast(const float4* __restrict__ v, ushort4* __restrict__ H) {
    const int n4 = BATCH * TOTAL / 4;
    int i = blockIdx.x * blockDim.x + threadIdx.x;
    const int stride = gridDim.x * blockDim.x;
    for (; i < n4; i += stride) {
        float4 f = v[i];
        ushort4 o;
        o.x = f2bf(fast_tanh(f.x));
        o.y = f2bf(fast_tanh(f.y));
        o.z = f2bf(fast_tanh(f.z));
        o.w = f2bf(fast_tanh(f.w));
        H[i] = o;
    }
}

__global__ void k_wcast(const float4* __restrict__ W, ushort4* __restrict__ Wb) {
    const int n4 = KGRP * BLK * BLK / 4;
    int i = blockIdx.x * blockDim.x + threadIdx.x;
    const int stride = gridDim.x * blockDim.x;
    for (; i < n4; i += stride) {
        float4 f = W[i];
        ushort4 o;
        o.x = f2bf(f.x); o.y = f2bf(f.y); o.z = f2bf(f.z); o.w = f2bf(f.w);
        Wb[i] = o;
    }
}

// ---------- pass 2: grouped GEMM, 256x256 tile, BK=64, 8 waves, 4-phase, counted vmcnt ----------
// C[m][n] = sum_k H[m][k] * W[n][k]; epilogue fuses x + bias.
//
// LDS: 2 buffers x (A[256][64] + B[256][64]) bf16 = 128 KiB, 1 block/CU.
// Swizzle (both-sides, rule #21): phys = log ^ (((log>>7)&7)<<4). 16 consecutive
// rows spread across all 8 16B-positions (8 lanes x 8 distinct rows per bank-group
// = the 8-cycle floor of a 1024B wave read). Pre-swizzled global source (LDS
// written linearly by global_load_lds) + same XOR on ds_read offsets.
//
// Staging units for tile T+1, issued during T (consumption-ordered):
//   ph0: u1 = A rows {0-63,128-191}   ph1: u2 = B rows {0-127}
//   ph2: u3 = B rows {128-255}        ph3: u4 = A rows {64-127,192-255}
// Counted waits (2 gload_lds per unit per wave), never 0 in the MAIN loop:
//   end ph1: vmcnt(4)  -> u4 of THIS tile landed (u1',u2' may fly)
//   end ph3: vmcnt(2)  -> u1..u3 of NEXT tile landed (u4' may fly)
// LAST TILE PEELED: no staging there, so the count-based waits would be no-ops
// (this was round-3's race: vmcnt(4) with only u4's 2 loads outstanding never
// waited -> ph2/ph3 of the final tile read stale A). The peeled tile does a
// one-time vmcnt(0) after ph1 instead.
// Race-freedom: each wave's ds_reads of a buffer retire (in-order lgkmcnt)
// before its MFMAs, hence before the tile-boundary barrier; first DMA into that
// buffer is issued after that barrier. Every vmcnt sits immediately before a
// barrier, publishing all waves' DMA shares (vmcnt is per-wave).

__global__ __launch_bounds__(512, 2)
void k_gemm(const unsigned short* __restrict__ H, const unsigned short* __restrict__ Wb,
            const float* __restrict__ x, const float* __restrict__ bias,
            float* __restrict__ out) {
    __shared__ __attribute__((aligned(1024))) char lds[131072];

    // T1: XCD swizzle. bid&7 == XCD; each XCD owns one group -> Wb[g] (2MB) L2-resident.
    const int bid   = blockIdx.x;              // 0..511
    const int g     = bid & 7;
    const int slot  = bid >> 3;                // 0..63
    const int mtile = slot >> 2;               // 0..15
    const int ntile = slot & 3;                // 0..3

    const int tid  = threadIdx.x;
    const int lane = tid & 63;
    const int w    = tid >> 6;                 // 0..7
    const int wr   = w >> 2;                   // 0..1  (M)
    const int wc   = w & 3;                    // 0..3  (N)

    // ds_read swizzled column bytes: kc[ks] = (ks*64 + (lane>>4)*16) ^ ((lane&7)<<4)
    uint32_t kc[2];
#pragma unroll
    for (int ks = 0; ks < 2; ++ks)
        kc[ks] = (uint32_t)((ks * 64 + ((lane >> 4) << 4)) ^ ((lane & 7) << 4));
    const uint32_t aRow = (uint32_t)(wr * 128 + (lane & 15)) * 128u;            // A region @0
    const uint32_t bRow = 32768u + (uint32_t)(wc * 64 + (lane & 15)) * 128u;    // B region @32K

    // staging source pre-swizzle: thread (w,lane) covers phys bytes c*8192+tid*16;
    // logical element there: row = c*64 + (tid>>3), colElem = ((lane&7) ^ ((lane>>3)&7)) * 8
    const int sRow = tid >> 3;                                   // 0..63 within 64-row chunk
    const int sCol = (((lane & 7) ^ ((lane >> 3) & 7)) << 3);    // element col 0..56
    const unsigned short* Asrc0 = H  + ((size_t)(mtile * 256) + sRow) * TOTAL + (size_t)g * BLK + sCol;
    const unsigned short* Bsrc0 = Wb + ((size_t)g * BLK * BLK) + ((size_t)(ntile * 256) + sRow) * BLK + sCol;
    const uint32_t ldsStageBase = (uint32_t)(w << 10);           // wave-uniform; HW adds lane*16

    auto stageA2 = [&](int kt, uint32_t bufb, int half) {        // half0: chunks {0,2}; half1: {1,3}
#pragma unroll
        for (int h = 0; h < 2; ++h) {
            const int c = half + h * 2;
            __builtin_amdgcn_global_load_lds(
                (const AS1 uint32_t*)(Asrc0 + (size_t)(c * 64) * TOTAL + kt * 64),
                (AS3 uint32_t*)(lds + bufb + c * 8192 + ldsStageBase), 16, 0, 0);
        }
    };
    auto stageB2 = [&](int kt, uint32_t bufb, int half) {        // half0: chunks {0,1}; half1: {2,3}
#pragma unroll
        for (int h = 0; h < 2; ++h) {
            const int c = half * 2 + h;
            __builtin_amdgcn_global_load_lds(
                (const AS1 uint32_t*)(Bsrc0 + (size_t)(c * 64) * BLK + kt * 64),
                (AS3 uint32_t*)(lds + bufb + 32768u + c * 8192 + ldsStageBase), 16, 0, 0);
        }
    };

    f32x4 acc[8][4];
#pragma unroll
    for (int m = 0; m < 8; ++m)
#pragma unroll
        for (int n = 0; n < 4; ++n) acc[m][n] = (f32x4){0.f, 0.f, 0.f, 0.f};

    // prologue: stage all of tile 0 into buf0 (u4 may stay in flight: vmcnt(2))
    stageA2(0, 0u, 0);
    stageB2(0, 0u, 0);
    stageB2(0, 0u, 1);
    stageA2(0, 0u, 1);
    asm volatile("s_waitcnt vmcnt(2)" ::: "memory");
    __builtin_amdgcn_s_barrier();
    __builtin_amdgcn_sched_barrier(0);

    uint32_t cur = 0;
    // ---------------- main loop: tiles 0..14, staging always on ----------------
    for (int kt = 0; kt < 15; ++kt) {
        const uint32_t bufb = cur << 16;
        const uint32_t nbuf = bufb ^ 65536u;
        const char* Lb = lds + bufb;

        short8 bfr[4][2];
        short8 am[2][2];

        // ---- phase 0: B all + A m0,m1 ----
#pragma unroll
        for (int n = 0; n < 4; ++n)
#pragma unroll
            for (int ks = 0; ks < 2; ++ks)
                bfr[n][ks] = *(const short8*)(Lb + bRow + n * 2048 + kc[ks]);
#pragma unroll
        for (int i = 0; i < 2; ++i)
#pragma unroll
            for (int ks = 0; ks < 2; ++ks)
                am[i][ks] = *(const short8*)(Lb + aRow + (0 + i) * 2048 + kc[ks]);
        stageA2(kt + 1, nbuf, 0);      // u1
        __builtin_amdgcn_s_barrier();
        __builtin_amdgcn_s_setprio(1);
#pragma unroll
        for (int i = 0; i < 2; ++i)
#pragma unroll
            for (int n = 0; n < 4; ++n)
#pragma unroll
                for (int ks = 0; ks < 2; ++ks)
                    acc[0 + i][n] = __builtin_amdgcn_mfma_f32_16x16x32_bf16(am[i][ks], bfr[n][ks], acc[0 + i][n], 0, 0, 0);
        __builtin_amdgcn_s_setprio(0);
        __builtin_amdgcn_s_barrier();

        // ---- phase 1: A m2,m3 ----
#pragma unroll
        for (int i = 0; i < 2; ++i)
#pragma unroll
            for (int ks = 0; ks < 2; ++ks)
                am[i][ks] = *(const short8*)(Lb + aRow + (2 + i) * 2048 + kc[ks]);
        stageB2(kt + 1, nbuf, 0);      // u2
        __builtin_amdgcn_s_barrier();
        __builtin_amdgcn_s_setprio(1);
#pragma unroll
        for (int i = 0; i < 2; ++i)
#pragma unroll
            for (int n = 0; n < 4; ++n)
#pragma unroll
                for (int ks = 0; ks < 2; ++ks)
                    acc[2 + i][n] = __builtin_amdgcn_mfma_f32_16x16x32_bf16(am[i][ks], bfr[n][ks], acc[2 + i][n], 0, 0, 0);
        __builtin_amdgcn_s_setprio(0);
        asm volatile("s_waitcnt vmcnt(4)" ::: "memory");   // u4 of THIS tile landed
        __builtin_amdgcn_s_barrier();

        // ---- phase 2: A m4,m5 ----
#pragma unroll
        for (int i = 0; i < 2; ++i)
#pragma unroll
            for (int ks = 0; ks < 2; ++ks)
                am[i][ks] = *(const short8*)(Lb + aRow + (4 + i) * 2048 + kc[ks]);
        stageB2(kt + 1, nbuf, 1);      // u3
        __builtin_amdgcn_s_barrier();
        __builtin_amdgcn_s_setprio(1);
#pragma unroll
        for (int i = 0; i < 2; ++i)
#pragma unroll
            for (int n = 0; n < 4; ++n)
#pragma unroll
                for (int ks = 0; ks < 2; ++ks)
                    acc[4 + i][n] = __builtin_amdgcn_mfma_f32_16x16x32_bf16(am[i][ks], bfr[n][ks], acc[4 + i][n], 0, 0, 0);
        __builtin_amdgcn_s_setprio(0);
        __builtin_amdgcn_s_barrier();

        // ---- phase 3: A m6,m7 ----
#pragma unroll
        for (int i = 0; i < 2; ++i)
#pragma unroll
            for (int ks = 0; ks < 2; ++ks)
                am[i][ks] = *(const short8*)(Lb + aRow + (6 + i) * 2048 + kc[ks]);
        stageA2(kt + 1, nbuf, 1);      // u4
        __builtin_amdgcn_s_barrier();
        __builtin_amdgcn_s_setprio(1);
#pragma unroll
        for (int i = 0; i < 2; ++i)
#pragma unroll
            for (int n = 0; n < 4; ++n)
#pragma unroll
                for (int ks = 0; ks < 2; ++ks)
                    acc[6 + i][n] = __builtin_amdgcn_mfma_f32_16x16x32_bf16(am[i][ks], bfr[n][ks], acc[6 + i][n], 0, 0, 0);
        __builtin_amdgcn_s_setprio(0);
        asm volatile("s_waitcnt vmcnt(2)" ::: "memory");   // u1..u3 of next tile landed
        __builtin_amdgcn_s_barrier();
        __builtin_amdgcn_sched_barrier(0);
        cur ^= 1u;
    }

    // ---------------- peeled last tile (kt=15): no staging ----------------
    {
        const char* Lb = lds + (cur << 16);
        short8 bfr[4][2];
        short8 am[2][2];

        // ---- phase 0: B all + A m0,m1 (u1..u3 landed via loop-exit vmcnt(2)) ----
#pragma unroll
        for (int n = 0; n < 4; ++n)
#pragma unroll
            for (int ks = 0; ks < 2; ++ks)
                bfr[n][ks] = *(const short8*)(Lb + bRow + n * 2048 + kc[ks]);
#pragma unroll
        for (int i = 0; i < 2; ++i)
#pragma unroll
            for (int ks = 0; ks < 2; ++ks)
                am[i][ks] = *(const short8*)(Lb + aRow + (0 + i) * 2048 + kc[ks]);
        __builtin_amdgcn_s_barrier();
        __builtin_amdgcn_s_setprio(1);
#pragma unroll
        for (int i = 0; i < 2; ++i)
#pragma unroll
            for (int n = 0; n < 4; ++n)
#pragma unroll
                for (int ks = 0; ks < 2; ++ks)
                    acc[0 + i][n] = __builtin_amdgcn_mfma_f32_16x16x32_bf16(am[i][ks], bfr[n][ks], acc[0 + i][n], 0, 0, 0);
        __builtin_amdgcn_s_setprio(0);
        __builtin_amdgcn_s_barrier();

        // ---- phase 1: A m2,m3; then one-time full drain (guards u4 of this tile) ----
#pragma unroll
        for (int i = 0; i < 2; ++i)
#pragma unroll
            for (int ks = 0; ks < 2; ++ks)
                am[i][ks] = *(const short8*)(Lb + aRow + (2 + i) * 2048 + kc[ks]);
        __builtin_amdgcn_s_barrier();
        __builtin_amdgcn_s_setprio(1);
#pragma unroll
        for (int i = 0; i < 2; ++i)
#pragma unroll
            for (int n = 0; n < 4; ++n)
#pragma unroll
                for (int ks = 0; ks < 2; ++ks)
                    acc[2 + i][n] = __builtin_amdgcn_mfma_f32_16x16x32_bf16(am[i][ks], bfr[n][ks], acc[2 + i][n], 0, 0, 0);
        __builtin_amdgcn_s_setprio(0);
        asm volatile("s_waitcnt vmcnt(0)" ::: "memory");   // u4 of the last tile landed
        __builtin_amdgcn_s_barrier();

        // ---- phase 2: A m4,m5 ----
#pragma unroll
        for (int i = 0; i < 2; ++i)
#pragma unroll
            for (int ks = 0; ks < 2; ++ks)
                am[i][ks] = *(const short8*)(Lb + aRow + (4 + i) * 2048 + kc[ks]);
        __builtin_amdgcn_s_barrier();
        __builtin_amdgcn_s_setprio(1);
#pragma unroll
        for (int i = 0; i < 2; ++i)
#pragma unroll
            for (int n = 0; n < 4; ++n)
#pragma unroll
                for (int ks = 0; ks < 2; ++ks)
                    acc[4 + i][n] = __builtin_amdgcn_mfma_f32_16x16x32_bf16(am[i][ks], bfr[n][ks], acc[4 + i][n], 0, 0, 0);
        __builtin_amdgcn_s_setprio(0);
        __builtin_amdgcn_s_barrier();

        // ---- phase 3: A m6,m7 ----
#pragma unroll
        for (int i = 0; i < 2; ++i)
#pragma unroll
            for (int ks = 0; ks < 2; ++ks)
                am[i][ks] = *(const short8*)(Lb + aRow + (6 + i) * 2048 + kc[ks]);
        __builtin_amdgcn_s_barrier();
        __builtin_amdgcn_s_setprio(1);
#pragma unroll
        for (int i = 0; i < 2; ++i)
#pragma unroll
            for (int n = 0; n < 4; ++n)
#pragma unroll
                for (int ks = 0; ks < 2; ++ks)
                    acc[6 + i][n] = __builtin_amdgcn_mfma_f32_16x16x32_bf16(am[i][ks], bfr[n][ks], acc[6 + i][n], 0, 0, 0);
        __builtin_amdgcn_s_setprio(0);
    }

    // ---------------- epilogue: out = x + bias + acc ----------------
    // C/D mapping (m89/m91): col = lane&15, row = (lane>>4)*4 + reg
    const int gout = (g + 1) & 7;
    const int row0 = mtile * 256 + wr * 128 + ((lane >> 4) << 2);
    const int colL = ntile * 256 + wc * 64 + (lane & 15);   // 0..1023 within group
    float bv[4];
#pragma unroll
    for (int n = 0; n < 4; ++n) bv[n] = bias[g * BLK + colL + n * 16];
#pragma unroll
    for (int m = 0; m < 8; ++m) {
#pragma unroll
        for (int j = 0; j < 4; ++j) {
            const int row = row0 + m * 16 + j;
            const size_t base = (size_t)row * TOTAL + (size_t)gout * BLK;
#pragma unroll
            for (int n = 0; n < 4; ++n) {
                const size_t idx = base + colL + n * 16;
                out[idx] = x[idx] + bv[n] + acc[m][n][j];
            }
        }
    }
}

// ---------- fallback (ws too small): correct but slow ----------

__global__ void k_naive(const float* __restrict__ x, const float* __restrict__ v,
                        const float* __restrict__ W, const float* __restrict__ b,
                        float* __restrict__ out) {
    __shared__ float hv[BLK];
    const int bid = blockIdx.x;
    const int quarter = bid & 3;
    const int g = (bid >> 2) & 7;
    const int row = bid >> 5;
    for (int i = threadIdx.x; i < BLK; i += 256)
        hv[i] = tanhf(v[(size_t)row * TOTAL + g * BLK + i]);
    __syncthreads();
    const int o = quarter * 256 + threadIdx.x;
    const float* wrow = W + ((size_t)g * BLK + o) * BLK;
    float s = 0.f;
    for (int i = 0; i < BLK; ++i) s += hv[i] * wrow[i];
    const size_t oi = (size_t)row * TOTAL + (size_t)((g + 1) & 7) * BLK + o;
    out[oi] = x[oi] + b[g * BLK + o] + s;
}

// ---------- launch ----------

extern "C" void kernel_launch(void* const* d_in, const int* in_sizes, int n_in,
                              void* d_out, int out_size, void* d_ws, size_t ws_size,
                              hipStream_t stream) {
    const float* x = (const float*)d_in[0];
    const float* v = (const float*)d_in[1];
    const float* W = (const float*)d_in[2];
    const float* b = (const float*)d_in[3];
    float* out = (float*)d_out;

    const size_t needH = (size_t)BATCH * TOTAL * sizeof(unsigned short);      // 64 MB
    const size_t needW = (size_t)KGRP * BLK * BLK * sizeof(unsigned short);   // 16 MB

    if (ws_size >= needH + needW) {
        unsigned short* H  = (unsigned short*)d_ws;
        unsigned short* Wb = (unsigned short*)((char*)d_ws + needH);
        k_tanh_cast<<<2048, 256, 0, stream>>>((const float4*)v, (ushort4*)H);
        k_wcast<<<1024, 256, 0, stream>>>((const float4*)W, (ushort4*)Wb);
        k_gemm<<<512, 512, 0, stream>>>(H, Wb, x, b, out);
    } else {
        k_naive<<<BATCH * KGRP * 4, 256, 0, stream>>>(x, v, W, b, out);
    }
}

// Round 5
// 153.836 us; speedup vs baseline: 1.0777x; 1.0110x over previous
//
#include <hip/hip_runtime.h>
#include <hip/hip_bf16.h>
#include <stdint.h>

#define BATCH 4096
#define KGRP  8
#define BLK   1024
#define TOTAL 8192

typedef __attribute__((ext_vector_type(8))) short short8;
typedef __attribute__((ext_vector_type(4))) float f32x4;

#define AS1 __attribute__((address_space(1)))
#define AS3 __attribute__((address_space(3)))

// ---------- helpers ----------

__device__ __forceinline__ unsigned short f2bf(float f) {
    union { float f; uint32_t u; } c; c.f = f;
    uint32_t u = c.u;
    u += 0x7fffu + ((u >> 16) & 1u);   // round-to-nearest-even
    return (unsigned short)(u >> 16);
}

__device__ __forceinline__ float fast_tanh(float x) {
    float e = __expf(2.0f * x);
    return 1.0f - 2.0f / (e + 1.0f);
}

// ---------- pass 1 (merged): tanh(v) -> bf16 H, W -> bf16 Wb ----------

__global__ void k_prep(const float4* __restrict__ v, ushort4* __restrict__ H,
                       const float4* __restrict__ W, ushort4* __restrict__ Wb) {
    const int b = blockIdx.x;
    if (b < 2048) {
        const int n4 = BATCH * TOTAL / 4;
        for (int i = b * 256 + threadIdx.x; i < n4; i += 2048 * 256) {
            float4 f = v[i];
            ushort4 o;
            o.x = f2bf(fast_tanh(f.x)); o.y = f2bf(fast_tanh(f.y));
            o.z = f2bf(fast_tanh(f.z)); o.w = f2bf(fast_tanh(f.w));
            H[i] = o;
        }
    } else {
        const int n4 = KGRP * BLK * BLK / 4;
        for (int i = (b - 2048) * 256 + threadIdx.x; i < n4; i += 512 * 256) {
            float4 f = W[i];
            ushort4 o;
            o.x = f2bf(f.x); o.y = f2bf(f.y); o.z = f2bf(f.z); o.w = f2bf(f.w);
            Wb[i] = o;
        }
    }
}

// ---------- pass 2: grouped GEMM, 256x256 tile, BK=64, 8 waves, 4-phase ----------
// C[m][n] = sum_k H[m][k] * W[n][k]; epilogue fuses x + bias.
//
// DEEP 2-TILE PREFETCH (this round's change). Consumption within a tile is
// front-loaded: B fully read at ph0; A chunks{0,2} (m0-3) by ph1; A chunks{1,3}
// (m4-7) by ph3. Each region is free one barrier after its consuming phase, so
// during tile T we stage:
//   ph0: A13(T+1) -> buf^1 (that buffer fully consumed at end of T-1)
//   ph1: B  (T+2) -> SAME buf (B region consumed at T.ph0)
//   ph2: A02(T+2) -> SAME buf (A02 region consumed at T.ph0/ph1)
// Issue->use distance: 6-7 phases (~1200+ cy) > HBM latency (~900 cy).
// Per-wave instr counts: A13=2, B=4, A02=2. Steady-state waits:
//   end-ph1: vmcnt(12)  guards A13(T)   [newer: B(T+2)4 + A13(T+1)2 + A02(T+1)2 + B(T+1)4]
//   end-ph3: vmcnt(8)   guards B,A02(T+1) [newer: A02(T+2)2 + B(T+2)4 + A13(T+1)2]
// Tail peeled (round-3 lesson: counts must stay exact when staging stops):
//   tile 14: stages only A13(15); waits vmcnt(8) / vmcnt(2)
//   tile 15: no staging; wait vmcnt(0) / none
// Race-freedom: every phase's ds_reads are consumed by that phase's MFMA
// (lgkm-retired before barrier arrival), and each region's stage is issued at
// least one barrier after its consuming phase; every vmcnt sits immediately
// before a barrier (vmcnt is per-wave; barrier publishes all shares).
//
// Swizzle (both-sides, rule #21): phys = log ^ (((log>>7)&7)<<4) — verified
// round 4: SQ_LDS_BANK_CONFLICT == 0.

__device__ __forceinline__ void stage_a(const unsigned short* Asrc0, char* ldsp,
                                        uint32_t bufb, uint32_t sb, int kt, int half) {
#pragma unroll
    for (int h = 0; h < 2; ++h) {
        const int c = half + h * 2;     // half0: chunks {0,2} = m0-3; half1: {1,3} = m4-7
        __builtin_amdgcn_global_load_lds(
            (const AS1 uint32_t*)(Asrc0 + (size_t)(c * 64) * TOTAL + kt * 64),
            (AS3 uint32_t*)(ldsp + bufb + c * 8192 + sb), 16, 0, 0);
    }
}

__device__ __forceinline__ void stage_b(const unsigned short* Bsrc0, char* ldsp,
                                        uint32_t bufb, uint32_t sb, int kt) {
#pragma unroll
    for (int c = 0; c < 4; ++c) {
        __builtin_amdgcn_global_load_lds(
            (const AS1 uint32_t*)(Bsrc0 + (size_t)(c * 64) * BLK + kt * 64),
            (AS3 uint32_t*)(ldsp + bufb + 32768u + c * 8192 + sb), 16, 0, 0);
    }
}

template<int N> __device__ __forceinline__ void waitvm() {
    if constexpr (N == 0)       asm volatile("s_waitcnt vmcnt(0)" ::: "memory");
    else if constexpr (N == 2)  asm volatile("s_waitcnt vmcnt(2)" ::: "memory");
    else if constexpr (N == 8)  asm volatile("s_waitcnt vmcnt(8)" ::: "memory");
    else if constexpr (N == 12) asm volatile("s_waitcnt vmcnt(12)" ::: "memory");
}

template<int M0>
__device__ __forceinline__ void mfma_phase(const short8 am[2][2], const short8 bfr[4][2],
                                           f32x4 (*acc)[4]) {
    __builtin_amdgcn_s_barrier();
    __builtin_amdgcn_s_setprio(1);
#pragma unroll
    for (int i = 0; i < 2; ++i)
#pragma unroll
        for (int n = 0; n < 4; ++n)
#pragma unroll
            for (int ks = 0; ks < 2; ++ks)
                acc[M0 + i][n] = __builtin_amdgcn_mfma_f32_16x16x32_bf16(am[i][ks], bfr[n][ks], acc[M0 + i][n], 0, 0, 0);
    __builtin_amdgcn_s_setprio(0);
}

template<bool SA13, bool SB, bool SA02, int W1, int W3>
__device__ __forceinline__ void tile_body(int kt, uint32_t bufb, char* ldsp,
                                          uint32_t aRow, uint32_t bRow, const uint32_t* kc,
                                          f32x4 (*acc)[4],
                                          const unsigned short* Asrc0, const unsigned short* Bsrc0,
                                          uint32_t sb) {
    const char* Lb = ldsp + bufb;
    short8 bfr[4][2], am[2][2];

    // ---- ph0: B all + A m0,m1 ; stage A13(kt+1) -> other buffer ----
#pragma unroll
    for (int n = 0; n < 4; ++n)
#pragma unroll
        for (int ks = 0; ks < 2; ++ks)
            bfr[n][ks] = *(const short8*)(Lb + bRow + n * 2048 + kc[ks]);
#pragma unroll
    for (int i = 0; i < 2; ++i)
#pragma unroll
        for (int ks = 0; ks < 2; ++ks)
            am[i][ks] = *(const short8*)(Lb + aRow + i * 2048 + kc[ks]);
    if constexpr (SA13) stage_a(Asrc0, ldsp, bufb ^ 65536u, sb, kt + 1, 1);
    mfma_phase<0>(am, bfr, acc);
    __builtin_amdgcn_s_barrier();

    // ---- ph1: A m2,m3 ; stage B(kt+2) -> same buffer ----
#pragma unroll
    for (int i = 0; i < 2; ++i)
#pragma unroll
        for (int ks = 0; ks < 2; ++ks)
            am[i][ks] = *(const short8*)(Lb + aRow + (2 + i) * 2048 + kc[ks]);
    if constexpr (SB) stage_b(Bsrc0, ldsp, bufb, sb, kt + 2);
    mfma_phase<2>(am, bfr, acc);
    waitvm<W1>();                 // A13(kt) landed -> ph2/ph3 reads safe
    __builtin_amdgcn_s_barrier();

    // ---- ph2: A m4,m5 ; stage A02(kt+2) -> same buffer ----
#pragma unroll
    for (int i = 0; i < 2; ++i)
#pragma unroll
        for (int ks = 0; ks < 2; ++ks)
            am[i][ks] = *(const short8*)(Lb + aRow + (4 + i) * 2048 + kc[ks]);
    if constexpr (SA02) stage_a(Asrc0, ldsp, bufb, sb, kt + 2, 0);
    mfma_phase<4>(am, bfr, acc);
    __builtin_amdgcn_s_barrier();

    // ---- ph3: A m6,m7 ----
#pragma unroll
    for (int i = 0; i < 2; ++i)
#pragma unroll
        for (int ks = 0; ks < 2; ++ks)
            am[i][ks] = *(const short8*)(Lb + aRow + (6 + i) * 2048 + kc[ks]);
    mfma_phase<6>(am, bfr, acc);
    if constexpr (W3 >= 0) {
        waitvm<W3>();             // B(kt+1)+A02(kt+1) landed -> next ph0 safe
        __builtin_amdgcn_s_barrier();
        __builtin_amdgcn_sched_barrier(0);
    }
}

__global__ __launch_bounds__(512, 2)
void k_gemm(const unsigned short* __restrict__ H, const unsigned short* __restrict__ Wb,
            const float* __restrict__ x, const float* __restrict__ bias,
            float* __restrict__ out) {
    __shared__ __attribute__((aligned(1024))) char lds[131072];
    char* ldsp = lds;

    // T1: XCD swizzle. bid&7 == XCD; each XCD owns one group -> Wb[g] (2MB) L2-resident.
    const int bid   = blockIdx.x;              // 0..511
    const int g     = bid & 7;
    const int slot  = bid >> 3;                // 0..63
    const int mtile = slot >> 2;               // 0..15
    const int ntile = slot & 3;                // 0..3

    const int tid  = threadIdx.x;
    const int lane = tid & 63;
    const int w    = tid >> 6;                 // 0..7
    const int wr   = w >> 2;                   // 0..1  (M)
    const int wc   = w & 3;                    // 0..3  (N)

    // ds_read swizzled column bytes: kc[ks] = (ks*64 + (lane>>4)*16) ^ ((lane&7)<<4)
    uint32_t kc[2];
#pragma unroll
    for (int ks = 0; ks < 2; ++ks)
        kc[ks] = (uint32_t)((ks * 64 + ((lane >> 4) << 4)) ^ ((lane & 7) << 4));
    const uint32_t aRow = (uint32_t)(wr * 128 + (lane & 15)) * 128u;            // A region @0
    const uint32_t bRow = 32768u + (uint32_t)(wc * 64 + (lane & 15)) * 128u;    // B region @32K

    // staging source pre-swizzle: thread tid covers phys bytes c*8192+tid*16;
    // logical element there: row = c*64 + (tid>>3), colElem = ((lane&7)^((lane>>3)&7))*8
    const int sRow = tid >> 3;
    const int sCol = (((lane & 7) ^ ((lane >> 3) & 7)) << 3);
    const unsigned short* Asrc0 = H  + ((size_t)(mtile * 256) + sRow) * TOTAL + (size_t)g * BLK + sCol;
    const unsigned short* Bsrc0 = Wb + ((size_t)g * BLK * BLK) + ((size_t)(ntile * 256) + sRow) * BLK + sCol;
    const uint32_t sb = (uint32_t)(w << 10);   // wave-uniform LDS base; HW adds lane*16

    f32x4 acc[8][4];
#pragma unroll
    for (int m = 0; m < 8; ++m)
#pragma unroll
        for (int n = 0; n < 4; ++n) acc[m][n] = (f32x4){0.f, 0.f, 0.f, 0.f};

    // prologue: full tile 0 + {B,A02} of tile 1 (issue order matters for counts)
    stage_b(Bsrc0, ldsp, 0u, sb, 0);
    stage_a(Asrc0, ldsp, 0u, sb, 0, 0);        // A02(0)
    stage_a(Asrc0, ldsp, 0u, sb, 0, 1);        // A13(0)
    stage_b(Bsrc0, ldsp, 65536u, sb, 1);
    stage_a(Asrc0, ldsp, 65536u, sb, 1, 0);    // A02(1)
    waitvm<8>();                               // B(0)+A02(0) landed; A13(0),B(1),A02(1) in flight
    __builtin_amdgcn_s_barrier();
    __builtin_amdgcn_sched_barrier(0);

    uint32_t cur = 0;
#pragma unroll 1
    for (int kt = 0; kt < 14; ++kt) {
        tile_body<true, true, true, 12, 8>(kt, cur << 16, ldsp, aRow, bRow, kc, acc, Asrc0, Bsrc0, sb);
        cur ^= 1u;
    }
    tile_body<true, false, false, 8, 2>(14, cur << 16, ldsp, aRow, bRow, kc, acc, Asrc0, Bsrc0, sb);
    cur ^= 1u;
    tile_body<false, false, false, 0, -1>(15, cur << 16, ldsp, aRow, bRow, kc, acc, Asrc0, Bsrc0, sb);

    // ---------------- epilogue: out = x + bias + acc ----------------
    // C/D mapping (m89/m91): col = lane&15, row = (lane>>4)*4 + reg
    const int gout = (g + 1) & 7;
    const int row0 = mtile * 256 + wr * 128 + ((lane >> 4) << 2);
    const int colL = ntile * 256 + wc * 64 + (lane & 15);   // 0..1023 within group
    float bv[4];
#pragma unroll
    for (int n = 0; n < 4; ++n) bv[n] = bias[g * BLK + colL + n * 16];
#pragma unroll
    for (int m = 0; m < 8; ++m) {
#pragma unroll
        for (int j = 0; j < 4; ++j) {
            const int row = row0 + m * 16 + j;
            const size_t base = (size_t)row * TOTAL + (size_t)gout * BLK;
#pragma unroll
            for (int n = 0; n < 4; ++n) {
                const size_t idx = base + colL + n * 16;
                out[idx] = x[idx] + bv[n] + acc[m][n][j];
            }
        }
    }
}

// ---------- fallback (ws too small): correct but slow ----------

__global__ void k_naive(const float* __restrict__ x, const float* __restrict__ v,
                        const float* __restrict__ W, const float* __restrict__ b,
                        float* __restrict__ out) {
    __shared__ float hv[BLK];
    const int bid = blockIdx.x;
    const int quarter = bid & 3;
    const int g = (bid >> 2) & 7;
    const int row = bid >> 5;
    for (int i = threadIdx.x; i < BLK; i += 256)
        hv[i] = tanhf(v[(size_t)row * TOTAL + g * BLK + i]);
    __syncthreads();
    const int o = quarter * 256 + threadIdx.x;
    const float* wrow = W + ((size_t)g * BLK + o) * BLK;
    float s = 0.f;
    for (int i = 0; i < BLK; ++i) s += hv[i] * wrow[i];
    const size_t oi = (size_t)row * TOTAL + (size_t)((g + 1) & 7) * BLK + o;
    out[oi] = x[oi] + b[g * BLK + o] + s;
}

// ---------- launch ----------

extern "C" void kernel_launch(void* const* d_in, const int* in_sizes, int n_in,
                              void* d_out, int out_size, void* d_ws, size_t ws_size,
                              hipStream_t stream) {
    const float* x = (const float*)d_in[0];
    const float* v = (const float*)d_in[1];
    const float* W = (const float*)d_in[2];
    const float* b = (const float*)d_in[3];
    float* out = (float*)d_out;

    const size_t needH = (size_t)BATCH * TOTAL * sizeof(unsigned short);      // 64 MB
    const size_t needW = (size_t)KGRP * BLK * BLK * sizeof(unsigned short);   // 16 MB

    if (ws_size >= needH + needW) {
        unsigned short* H  = (unsigned short*)d_ws;
        unsigned short* Wb = (unsigned short*)((char*)d_ws + needH);
        k_prep<<<2560, 256, 0, stream>>>((const float4*)v, (ushort4*)H,
                                         (const float4*)W, (ushort4*)Wb);
        k_gemm<<<512, 512, 0, stream>>>(H, Wb, x, b, out);
    } else {
        k_naive<<<BATCH * KGRP * 4, 256, 0, stream>>>(x, v, W, b, out);
    }
}